// Round 7
// baseline (350.647 us; speedup 1.0000x reference)
//
#include <hip/hip_runtime.h>
#include <hip/hip_bf16.h>
#include <stdint.h>
#include <math.h>

#define NR 16384
#define DIM 768
#define KEPS 1e-8f

#define BM 128          // tile edge
#define BK 64           // staged K per tile
#define NB (NR / BM)    // 128 row/col blocks
#define KT (DIM / BK)   // 12 k-tiles
#define NTILES (NB * (NB + 1) / 2)   // 8256 upper-triangle tiles

typedef __attribute__((ext_vector_type(4))) float f32x4;

__device__ inline uint32_t fkey(float f) {
    union { float f; uint32_t u; } v; v.f = f;
    return (v.u & 0x80000000u) ? ~v.u : (v.u | 0x80000000u);
}

__device__ inline unsigned long long pack_vc(float v, int c) {
    return ((unsigned long long)fkey(v) << 32) | (unsigned)c;
}

__device__ inline void gload16(const uint8_t* g, const uint8_t* l) {
    __builtin_amdgcn_global_load_lds(
        (const __attribute__((address_space(1))) void*)g,
        (__attribute__((address_space(3))) void*)l,
        16, 0, 0);
}

// fp32 -> OCP e4m3fn (round-nearest-even-ish; exactness irrelevant: fp8 only
// drives neighbor SELECTION, the refine pass recomputes distances in fp32)
__device__ inline uint8_t f2fp8(float f) {
    union { float f; uint32_t u; } v; v.f = f;
    const uint8_t s = (uint8_t)((v.u >> 24) & 0x80u);
    float a = fabsf(f);
    if (a >= 448.0f) return s | 0x7E;            // clamp to max normal
    if (a < 0.015625f) {                         // below 2^-6: subnormal
        int q = (int)rintf(a * 512.0f);          // multiples of 2^-9
        if (q >= 8) return s | 0x08;
        return s | (uint8_t)q;
    }
    int ex; float m = frexpf(a, &ex);            // a = m * 2^ex, m in [0.5,1)
    int E = ex + 6;                              // e4m3 biased exp
    int frac = (int)rintf(m * 16.0f - 8.0f);     // 0..8
    if (frac >= 8) { frac = 0; ++E; if (E > 15) return s | 0x7E; }
    return s | (uint8_t)(E << 3) | (uint8_t)frac;
}

// ------------- Kernel 1: row L2-normalize, fp32 -> fp8 + norms ---------------
__global__ __launch_bounds__(256) void k_norm(const float* __restrict__ X,
                                              uint8_t* __restrict__ Xn,
                                              float* __restrict__ norms) {
    const int wid = threadIdx.x >> 6, lane = threadIdx.x & 63;
    const int row = blockIdx.x * 4 + wid;
    const float4* xr = (const float4*)(X + (size_t)row * DIM) + lane * 3;
    float4 a = xr[0], b = xr[1], c = xr[2];
    float s = a.x*a.x + a.y*a.y + a.z*a.z + a.w*a.w
            + b.x*b.x + b.y*b.y + b.z*b.z + b.w*b.w
            + c.x*c.x + c.y*c.y + c.z*c.z + c.w*c.w;
#pragma unroll
    for (int m = 32; m >= 1; m >>= 1) s += __shfl_xor(s, m);
    const float n = sqrtf(s);
    if (lane == 0) norms[row] = n;
    const float rn = 1.0f / fmaxf(n, KEPS);
    float v[12] = {a.x,a.y,a.z,a.w,b.x,b.y,b.z,b.w,c.x,c.y,c.z,c.w};
    uint8_t q[12];
#pragma unroll
    for (int i = 0; i < 12; ++i) q[i] = f2fp8(v[i] * rn);
    uint32_t* dst = (uint32_t*)(Xn + (size_t)row * DIM + lane * 12);
    dst[0] = (uint32_t)q[0] | ((uint32_t)q[1] << 8) | ((uint32_t)q[2] << 16) | ((uint32_t)q[3] << 24);
    dst[1] = (uint32_t)q[4] | ((uint32_t)q[5] << 8) | ((uint32_t)q[6] << 16) | ((uint32_t)q[7] << 24);
    dst[2] = (uint32_t)q[8] | ((uint32_t)q[9] << 8) | ((uint32_t)q[10] << 16) | ((uint32_t)q[11] << 24);
}

// ---------------- Kernel 1b: init (value, index) max keys --------------------
__global__ __launch_bounds__(256) void k_init(unsigned long long* __restrict__ nn64) {
    nn64[blockIdx.x * 256 + threadIdx.x] = pack_vc(-2.0f, 0);
}

// ------ Kernel 2: fp8 128^2 upper-tri tile, single-buffer, 4 blk/CU ----------
// R5 structure (proven 27.5% MfmaUtil = LDS-BW ceiling at 32 FLOP/B); fp8
// doubles FLOP/LDS-byte to 64. Regions [128][64B]; 16B-slot swizzle
// c' = c ^ ((r>>1)&3) puts the 16-lane ds_read_b64 groups at the bank floor
// (rows r, r+8 pair on a quad = free 2-way).
__global__ __launch_bounds__(256, 4) void k_maxdot(const uint8_t* __restrict__ Xn,
                                                   unsigned long long* __restrict__ nn64) {
    __shared__ uint8_t lA[BM * BK];
    __shared__ uint8_t lB[BM * BK];
    const int tid  = threadIdx.x;
    const int lane = tid & 63, wid = tid >> 6;
    const int wr = wid >> 1, wc = wid & 1;
    const int l15 = lane & 15, lhi = lane >> 4;

    // XCD-chunked bijective swizzle (NTILES % 8 == 0)
    int t = (int)blockIdx.x;
    t = (t & 7) * (NTILES / 8) + (t >> 3);
    // decode tile id -> (rb, cb), cb >= rb   [S(rb) = rb*(257-rb)/2]
    float disc = 66049.0f - 8.0f * (float)t;
    int rb = (int)((257.0f - sqrtf(disc)) * 0.5f);
    if (rb > NB - 1) rb = NB - 1;
    if (rb < 0) rb = 0;
    while (rb > 0 && rb * (257 - rb) / 2 > t) --rb;
    while ((rb + 1) * (257 - (rb + 1)) / 2 <= t) ++rb;
    const int cb = rb + (t - rb * (257 - rb) / 2);
    const int rowbase = rb * BM;
    const int colbase = cb * BM;
    const bool diag = (rb == cb);

    f32x4 acc[4][4];
    const f32x4 z = {0.f, 0.f, 0.f, 0.f};
#pragma unroll
    for (int i = 0; i < 4; ++i)
#pragma unroll
        for (int j = 0; j < 4; ++j) acc[i][j] = z;

    // staging: row = it*64 + tid/4, 16B chunk = tid&3, source chunk swizzled
    const int s_r0 = tid >> 2;
    const int s_c  = tid & 3;

    for (int kt = 0; kt < KT; ++kt) {
#pragma unroll
        for (int it = 0; it < 2; ++it) {
            const int r = it * 64 + s_r0;
            const int c = s_c ^ ((r >> 1) & 3);
            const size_t koff = (size_t)kt * BK + c * 16;
            gload16(Xn + (size_t)(rowbase + r) * DIM + koff, lA + it * 4096 + wid * 1024);
            gload16(Xn + (size_t)(colbase + r) * DIM + koff, lB + it * 4096 + wid * 1024);
        }
        __syncthreads();     // vmcnt(0) drain; hidden by 4 co-resident blocks
#pragma unroll
        for (int ks = 0; ks < 2; ++ks) {
            long af[4], bg[4];
            const int s16 = ks * 2 + (lhi >> 1);
            const int lo8 = (lhi & 1) * 8;
#pragma unroll
            for (int mf = 0; mf < 4; ++mf) {
                const int r = wr * 64 + mf * 16 + l15;
                af[mf] = *(const long*)(lA + r * 64 + ((s16 ^ ((r >> 1) & 3)) << 4) + lo8);
            }
#pragma unroll
            for (int nf = 0; nf < 4; ++nf) {
                const int r = wc * 64 + nf * 16 + l15;
                bg[nf] = *(const long*)(lB + r * 64 + ((s16 ^ ((r >> 1) & 3)) << 4) + lo8);
            }
#pragma unroll
            for (int mf = 0; mf < 4; ++mf)
#pragma unroll
                for (int nf = 0; nf < 4; ++nf)
                    acc[mf][nf] = __builtin_amdgcn_mfma_f32_16x16x32_fp8_fp8(
                        af[mf], bg[nf], acc[mf][nf], 0, 0, 0);
        }
        __syncthreads();
    }

    // diagonal tiles: mask self-similarity to -1 (reference semantics)
    if (diag) {
#pragma unroll
        for (int mf = 0; mf < 4; ++mf)
#pragma unroll
            for (int nf = 0; nf < 4; ++nf)
#pragma unroll
                for (int rr = 0; rr < 4; ++rr) {
                    const int rl = wr * 64 + mf * 16 + lhi * 4 + rr;
                    const int cl = wc * 64 + nf * 16 + l15;
                    if (rl == cl) acc[mf][nf][rr] = -1.0f;
                }
    }

    // ---- row-max with argmax col: nf regs -> 16 cols (lane bits 0..3) ----
#pragma unroll
    for (int mf = 0; mf < 4; ++mf)
#pragma unroll
        for (int rr = 0; rr < 4; ++rr) {
            float v = acc[mf][0][rr];
            int   c = colbase + wc * 64 + l15;
#pragma unroll
            for (int nf = 1; nf < 4; ++nf) {
                const float w2 = acc[mf][nf][rr];
                const int   c2 = colbase + wc * 64 + nf * 16 + l15;
                if (w2 > v) { v = w2; c = c2; }
            }
#pragma unroll
            for (int m = 1; m <= 8; m <<= 1) {
                const float ov = __shfl_xor(v, m);
                const int   oc = __shfl_xor(c, m);
                if (ov > v) { v = ov; c = oc; }
            }
            if (l15 == 0) {
                const int r = rowbase + wr * 64 + mf * 16 + lhi * 4 + rr;
                atomicMax(&nn64[r], pack_vc(v, c));
            }
        }

    // ---- col-max with argmax row: mf,rr regs -> row-groups (bits 4,5) ----
#pragma unroll
    for (int nf = 0; nf < 4; ++nf) {
        float v = acc[0][nf][0];
        int   c = rowbase + wr * 64 + lhi * 4;
#pragma unroll
        for (int mf = 0; mf < 4; ++mf)
#pragma unroll
            for (int rr = 0; rr < 4; ++rr) {
                if (mf == 0 && rr == 0) continue;
                const float w2 = acc[mf][nf][rr];
                const int   c2 = rowbase + wr * 64 + mf * 16 + lhi * 4 + rr;
                if (w2 > v) { v = w2; c = c2; }
            }
#pragma unroll
        for (int m = 16; m <= 32; m <<= 1) {
            const float ov = __shfl_xor(v, m);
            const int   oc = __shfl_xor(c, m);
            if (ov > v) { v = ov; c = oc; }
        }
        if ((lane >> 4) == 0) {
            const int cc = colbase + wc * 64 + nf * 16 + l15;
            atomicMax(&nn64[cc], pack_vc(v, c));
        }
    }
}

// --- Kernel 3: fp32 exact refine — reference distance for selected neighbor --
__global__ __launch_bounds__(256) void k_refine(const float* __restrict__ X,
                                                const float* __restrict__ norms,
                                                const unsigned long long* __restrict__ nn64,
                                                float* __restrict__ logd) {
    const int wid = threadIdx.x >> 6, lane = threadIdx.x & 63;
    const int r = blockIdx.x * 4 + wid;
    const int j = (int)(nn64[r] & 0xFFFFu);
    const float rnr = 1.0f / fmaxf(norms[r], KEPS);
    const float rnj = 1.0f / fmaxf(norms[j], KEPS);
    const float4* xr = (const float4*)(X + (size_t)r * DIM) + lane * 3;
    const float4* xj = (const float4*)(X + (size_t)j * DIM) + lane * 3;
    float s = 0.0f;
#pragma unroll
    for (int i = 0; i < 3; ++i) {
        const float4 a = xr[i], b = xj[i];
        float d;
        d = a.x * rnr - b.x * rnj + KEPS; s = fmaf(d, d, s);
        d = a.y * rnr - b.y * rnj + KEPS; s = fmaf(d, d, s);
        d = a.z * rnr - b.z * rnj + KEPS; s = fmaf(d, d, s);
        d = a.w * rnr - b.w * rnj + KEPS; s = fmaf(d, d, s);
    }
#pragma unroll
    for (int m = 32; m >= 1; m >>= 1) s += __shfl_xor(s, m);
    if (lane == 0) logd[r] = logf(sqrtf(s) + KEPS);
}

// ---------------- Kernel 4: deterministic mean of log-distances --------------
__global__ __launch_bounds__(256) void k_loss(const float* __restrict__ logd,
                                              float* __restrict__ out) {
    float local = 0.0f;
    for (int r = threadIdx.x; r < NR; r += 256) local += logd[r];
#pragma unroll
    for (int m = 32; m >= 1; m >>= 1) local += __shfl_xor(local, m);
    __shared__ float red[4];
    const int lane = threadIdx.x & 63, wid = threadIdx.x >> 6;
    if (lane == 0) red[wid] = local;
    __syncthreads();
    if (threadIdx.x == 0)
        out[0] = -(red[0] + red[1] + red[2] + red[3]) / (float)NR;
}

extern "C" void kernel_launch(void* const* d_in, const int* in_sizes, int n_in,
                              void* d_out, int out_size, void* d_ws, size_t ws_size,
                              hipStream_t stream) {
    const float* X = (const float*)d_in[0];
    float* out = (float*)d_out;
    uint8_t* Xn = (uint8_t*)d_ws;                                  // 12.6 MiB fp8
    char* p = (char*)d_ws + (size_t)NR * DIM;                      // aligned (768B rows)
    float* norms = (float*)p;                 p += (size_t)NR * 4; // 64 KiB
    unsigned long long* nn64 = (unsigned long long*)p; p += (size_t)NR * 8; // 128 KiB
    float* logd = (float*)p;                                       // 64 KiB

    k_norm<<<NR / 4, 256, 0, stream>>>(X, Xn, norms);
    k_init<<<NR / 256, 256, 0, stream>>>(nn64);
    k_maxdot<<<NTILES, 256, 0, stream>>>(Xn, nn64);
    k_refine<<<NR / 4, 256, 0, stream>>>(X, norms, nn64, logd);
    k_loss<<<1, 256, 0, stream>>>(logd, out);
}

// Round 8
// 307.852 us; speedup vs baseline: 1.1390x; 1.1390x over previous
//
#include <hip/hip_runtime.h>
#include <hip/hip_bf16.h>
#include <stdint.h>
#include <math.h>

#define NR 16384
#define DIM 768
#define KEPS 1e-8f

#define BM 128          // tile edge
#define BK 64           // staged K per tile
#define NB (NR / BM)    // 128 row/col blocks
#define KT (DIM / BK)   // 12 k-tiles
#define NTILES (NB * (NB + 1) / 2)   // 8256 upper-triangle tiles

typedef __attribute__((ext_vector_type(4))) float f32x4;

__device__ inline uint32_t fkey(float f) {
    union { float f; uint32_t u; } v; v.f = f;
    return (v.u & 0x80000000u) ? ~v.u : (v.u | 0x80000000u);
}

__device__ inline unsigned long long pack_vc(float v, int c) {
    return ((unsigned long long)fkey(v) << 32) | (unsigned)c;
}

__device__ inline void gload16(const uint8_t* g, const uint8_t* l) {
    __builtin_amdgcn_global_load_lds(
        (const __attribute__((address_space(1))) void*)g,
        (__attribute__((address_space(3))) void*)l,
        16, 0, 0);
}

// fp32 -> OCP e4m3fn (selection only; refine pass recomputes exact fp32)
__device__ inline uint8_t f2fp8(float f) {
    union { float f; uint32_t u; } v; v.f = f;
    const uint8_t s = (uint8_t)((v.u >> 24) & 0x80u);
    float a = fabsf(f);
    if (a >= 448.0f) return s | 0x7E;
    if (a < 0.015625f) {
        int q = (int)rintf(a * 512.0f);
        if (q >= 8) return s | 0x08;
        return s | (uint8_t)q;
    }
    int ex; float m = frexpf(a, &ex);
    int E = ex + 6;
    int frac = (int)rintf(m * 16.0f - 8.0f);
    if (frac >= 8) { frac = 0; ++E; if (E > 15) return s | 0x7E; }
    return s | (uint8_t)(E << 3) | (uint8_t)frac;
}

// ---- Kernel 1: row L2-normalize, fp32 -> fp8, rows with (row&8) get their ----
// ---- 8-byte halves swapped inside every 16B chunk (LDS bank-swizzle bit) ----
__global__ __launch_bounds__(256) void k_norm(const float* __restrict__ X,
                                              uint8_t* __restrict__ Xn,
                                              float* __restrict__ norms) {
    __shared__ uint8_t buf[4][768];
    const int wid = threadIdx.x >> 6, lane = threadIdx.x & 63;
    const int row = blockIdx.x * 4 + wid;
    const float4* xr = (const float4*)(X + (size_t)row * DIM) + lane * 3;
    float4 a = xr[0], b = xr[1], c = xr[2];
    float s = a.x*a.x + a.y*a.y + a.z*a.z + a.w*a.w
            + b.x*b.x + b.y*b.y + b.z*b.z + b.w*b.w
            + c.x*c.x + c.y*c.y + c.z*c.z + c.w*c.w;
#pragma unroll
    for (int m = 32; m >= 1; m >>= 1) s += __shfl_xor(s, m);
    const float n = sqrtf(s);
    if (lane == 0) norms[row] = n;
    const float rn = 1.0f / fmaxf(n, KEPS);
    float v[12] = {a.x,a.y,a.z,a.w,b.x,b.y,b.z,b.w,c.x,c.y,c.z,c.w};
    uint8_t q[12];
#pragma unroll
    for (int i = 0; i < 12; ++i) q[i] = f2fp8(v[i] * rn);
    uint32_t* lb = (uint32_t*)&buf[wid][lane * 12];
    lb[0] = (uint32_t)q[0] | ((uint32_t)q[1] << 8) | ((uint32_t)q[2]  << 16) | ((uint32_t)q[3]  << 24);
    lb[1] = (uint32_t)q[4] | ((uint32_t)q[5] << 8) | ((uint32_t)q[6]  << 16) | ((uint32_t)q[7]  << 24);
    lb[2] = (uint32_t)q[8] | ((uint32_t)q[9] << 8) | ((uint32_t)q[10] << 16) | ((uint32_t)q[11] << 24);
    __syncthreads();
    if (lane < 48) {
        const uint2* pb = (const uint2*)&buf[wid][lane * 16];
        uint2 lo = pb[0], hi = pb[1];
        uint4 o;
        if (row & 8) o = make_uint4(hi.x, hi.y, lo.x, lo.y);
        else         o = make_uint4(lo.x, lo.y, hi.x, hi.y);
        *(uint4*)(Xn + (size_t)row * DIM + lane * 16) = o;
    }
}

// ---------------- Kernel 1b: init (value, index) max keys --------------------
__global__ __launch_bounds__(256) void k_init(unsigned long long* __restrict__ nn64) {
    nn64[blockIdx.x * 256 + threadIdx.x] = pack_vc(-2.0f, 0);
}

// ------ Kernel 2: fp8 128^2 upper-tri tile, single-buffer, 4 blk/CU ----------
// Read swizzle: addr = r*64 + ((s16^((r>>1)&3))<<4) + (lo8 ^ (r&8)).
// Bank-start over a 16-lane group = 16*(l15&1) + 4*(s16^((l15>>1)&3))
// + 2*((lhi&1)^((l15>>3)&1)) -> all 16 even positions once -> 32 banks
// covered exactly once (R7's missing 2-bank bit; conflicts 2.5e7 -> 0).
// The lo8^ (r&8) half-swap is pre-baked into Xn by k_norm.
__global__ __launch_bounds__(256, 4) void k_maxdot(const uint8_t* __restrict__ Xn,
                                                   unsigned long long* __restrict__ nn64) {
    __shared__ uint8_t lA[BM * BK];
    __shared__ uint8_t lB[BM * BK];
    const int tid  = threadIdx.x;
    const int lane = tid & 63, wid = tid >> 6;
    const int wr = wid >> 1, wc = wid & 1;
    const int l15 = lane & 15, lhi = lane >> 4;

    // XCD-chunked bijective swizzle (NTILES % 8 == 0)
    int t = (int)blockIdx.x;
    t = (t & 7) * (NTILES / 8) + (t >> 3);
    // decode tile id -> (rb, cb), cb >= rb   [S(rb) = rb*(257-rb)/2]
    float disc = 66049.0f - 8.0f * (float)t;
    int rb = (int)((257.0f - sqrtf(disc)) * 0.5f);
    if (rb > NB - 1) rb = NB - 1;
    if (rb < 0) rb = 0;
    while (rb > 0 && rb * (257 - rb) / 2 > t) --rb;
    while ((rb + 1) * (257 - (rb + 1)) / 2 <= t) ++rb;
    const int cb = rb + (t - rb * (257 - rb) / 2);
    const int rowbase = rb * BM;
    const int colbase = cb * BM;
    const bool diag = (rb == cb);

    f32x4 acc[4][4];
    const f32x4 z = {0.f, 0.f, 0.f, 0.f};
#pragma unroll
    for (int i = 0; i < 4; ++i)
#pragma unroll
        for (int j = 0; j < 4; ++j) acc[i][j] = z;

    // staging: row = it*64 + tid/4, 16B chunk = tid&3, source chunk swizzled
    const int s_r0 = tid >> 2;
    const int s_c  = tid & 3;

    for (int kt = 0; kt < KT; ++kt) {
#pragma unroll
        for (int it = 0; it < 2; ++it) {
            const int r = it * 64 + s_r0;
            const int c = s_c ^ ((r >> 1) & 3);
            const size_t koff = (size_t)kt * BK + c * 16;
            gload16(Xn + (size_t)(rowbase + r) * DIM + koff, lA + it * 4096 + wid * 1024);
            gload16(Xn + (size_t)(colbase + r) * DIM + koff, lB + it * 4096 + wid * 1024);
        }
        __syncthreads();     // vmcnt(0) drain; hidden by 4 co-resident blocks
#pragma unroll
        for (int ks = 0; ks < 2; ++ks) {
            long af[4], bg[4];
            const int s16 = ks * 2 + (lhi >> 1);
            const int lo8 = (lhi & 1) * 8;
#pragma unroll
            for (int mf = 0; mf < 4; ++mf) {
                const int r = wr * 64 + mf * 16 + l15;
                af[mf] = *(const long*)(lA + r * 64 + ((s16 ^ ((r >> 1) & 3)) << 4) + (lo8 ^ (r & 8)));
            }
#pragma unroll
            for (int nf = 0; nf < 4; ++nf) {
                const int r = wc * 64 + nf * 16 + l15;
                bg[nf] = *(const long*)(lB + r * 64 + ((s16 ^ ((r >> 1) & 3)) << 4) + (lo8 ^ (r & 8)));
            }
#pragma unroll
            for (int mf = 0; mf < 4; ++mf)
#pragma unroll
                for (int nf = 0; nf < 4; ++nf)
                    acc[mf][nf] = __builtin_amdgcn_mfma_f32_16x16x32_fp8_fp8(
                        af[mf], bg[nf], acc[mf][nf], 0, 0, 0);
        }
        __syncthreads();
    }

    // diagonal tiles: mask self-similarity to -1 (reference semantics)
    if (diag) {
#pragma unroll
        for (int mf = 0; mf < 4; ++mf)
#pragma unroll
            for (int nf = 0; nf < 4; ++nf)
#pragma unroll
                for (int rr = 0; rr < 4; ++rr) {
                    const int rl = wr * 64 + mf * 16 + lhi * 4 + rr;
                    const int cl = wc * 64 + nf * 16 + l15;
                    if (rl == cl) acc[mf][nf][rr] = -1.0f;
                }
    }

    // ---- row-max with argmax col: nf regs -> 16 cols (lane bits 0..3) ----
#pragma unroll
    for (int mf = 0; mf < 4; ++mf)
#pragma unroll
        for (int rr = 0; rr < 4; ++rr) {
            float v = acc[mf][0][rr];
            int   c = colbase + wc * 64 + l15;
#pragma unroll
            for (int nf = 1; nf < 4; ++nf) {
                const float w2 = acc[mf][nf][rr];
                const int   c2 = colbase + wc * 64 + nf * 16 + l15;
                if (w2 > v) { v = w2; c = c2; }
            }
#pragma unroll
            for (int m = 1; m <= 8; m <<= 1) {
                const float ov = __shfl_xor(v, m);
                const int   oc = __shfl_xor(c, m);
                if (ov > v) { v = ov; c = oc; }
            }
            if (l15 == 0) {
                const int r = rowbase + wr * 64 + mf * 16 + lhi * 4 + rr;
                atomicMax(&nn64[r], pack_vc(v, c));
            }
        }

    // ---- col-max with argmax row: mf,rr regs -> row-groups (bits 4,5) ----
#pragma unroll
    for (int nf = 0; nf < 4; ++nf) {
        float v = acc[0][nf][0];
        int   c = rowbase + wr * 64 + lhi * 4;
#pragma unroll
        for (int mf = 0; mf < 4; ++mf)
#pragma unroll
            for (int rr = 0; rr < 4; ++rr) {
                if (mf == 0 && rr == 0) continue;
                const float w2 = acc[mf][nf][rr];
                const int   c2 = rowbase + wr * 64 + mf * 16 + lhi * 4 + rr;
                if (w2 > v) { v = w2; c = c2; }
            }
#pragma unroll
        for (int m = 16; m <= 32; m <<= 1) {
            const float ov = __shfl_xor(v, m);
            const int   oc = __shfl_xor(c, m);
            if (ov > v) { v = ov; c = oc; }
        }
        if ((lane >> 4) == 0) {
            const int cc = colbase + wc * 64 + nf * 16 + l15;
            atomicMax(&nn64[cc], pack_vc(v, c));
        }
    }
}

// --- Kernel 3: fp32 exact refine — reference distance for selected neighbor --
__global__ __launch_bounds__(256) void k_refine(const float* __restrict__ X,
                                                const float* __restrict__ norms,
                                                const unsigned long long* __restrict__ nn64,
                                                float* __restrict__ logd) {
    const int wid = threadIdx.x >> 6, lane = threadIdx.x & 63;
    const int r = blockIdx.x * 4 + wid;
    const int j = (int)(nn64[r] & 0xFFFFu);
    const float rnr = 1.0f / fmaxf(norms[r], KEPS);
    const float rnj = 1.0f / fmaxf(norms[j], KEPS);
    const float4* xr = (const float4*)(X + (size_t)r * DIM) + lane * 3;
    const float4* xj = (const float4*)(X + (size_t)j * DIM) + lane * 3;
    float s = 0.0f;
#pragma unroll
    for (int i = 0; i < 3; ++i) {
        const float4 a = xr[i], b = xj[i];
        float d;
        d = a.x * rnr - b.x * rnj + KEPS; s = fmaf(d, d, s);
        d = a.y * rnr - b.y * rnj + KEPS; s = fmaf(d, d, s);
        d = a.z * rnr - b.z * rnj + KEPS; s = fmaf(d, d, s);
        d = a.w * rnr - b.w * rnj + KEPS; s = fmaf(d, d, s);
    }
#pragma unroll
    for (int m = 32; m >= 1; m >>= 1) s += __shfl_xor(s, m);
    if (lane == 0) logd[r] = logf(sqrtf(s) + KEPS);
}

// ---------------- Kernel 4: deterministic mean of log-distances --------------
__global__ __launch_bounds__(256) void k_loss(const float* __restrict__ logd,
                                              float* __restrict__ out) {
    float local = 0.0f;
    for (int r = threadIdx.x; r < NR; r += 256) local += logd[r];
#pragma unroll
    for (int m = 32; m >= 1; m >>= 1) local += __shfl_xor(local, m);
    __shared__ float red[4];
    const int lane = threadIdx.x & 63, wid = threadIdx.x >> 6;
    if (lane == 0) red[wid] = local;
    __syncthreads();
    if (threadIdx.x == 0)
        out[0] = -(red[0] + red[1] + red[2] + red[3]) / (float)NR;
}

extern "C" void kernel_launch(void* const* d_in, const int* in_sizes, int n_in,
                              void* d_out, int out_size, void* d_ws, size_t ws_size,
                              hipStream_t stream) {
    const float* X = (const float*)d_in[0];
    float* out = (float*)d_out;
    uint8_t* Xn = (uint8_t*)d_ws;                                  // 12.6 MiB fp8
    char* p = (char*)d_ws + (size_t)NR * DIM;
    float* norms = (float*)p;                 p += (size_t)NR * 4;
    unsigned long long* nn64 = (unsigned long long*)p; p += (size_t)NR * 8;
    float* logd = (float*)p;

    k_norm<<<NR / 4, 256, 0, stream>>>(X, Xn, norms);
    k_init<<<NR / 256, 256, 0, stream>>>(nn64);
    k_maxdot<<<NTILES, 256, 0, stream>>>(Xn, nn64);
    k_refine<<<NR / 4, 256, 0, stream>>>(X, norms, nn64, logd);
    k_loss<<<1, 256, 0, stream>>>(logd, out);
}